// Round 5
// baseline (154.953 us; speedup 1.0000x reference)
//
#include <hip/hip_runtime.h>

typedef __attribute__((ext_vector_type(8))) short short8;
typedef __attribute__((ext_vector_type(4))) float f32x4;

#define INF 4096
#define NKT 40              // 5 chunks * 8 K-tiles of 32  (K = 5*256 = 1280)
#define BUFB 24576          // bytes per K-tile buffer (A 8KB + B 16KB)

#define AS1 __attribute__((address_space(1)))
#define AS3 __attribute__((address_space(3)))

__device__ __forceinline__ unsigned short f2bf(float f) {
    unsigned int u = __float_as_uint(f);
    u += 0x7FFFu + ((u >> 16) & 1u);
    return (unsigned short)(u >> 16);
}

__device__ __forceinline__ void gl_lds16(const unsigned short* g, void* l) {
    __builtin_amdgcn_global_load_lds((const AS1 void*)g, (AS3 void*)l, 16, 0, 0);
}

// swizzle within a [R][32]-bf16 tile (64B rows): XOR byte bits {4,5} with row
// bits {1,2}. Involution, 16B-aligned. Fragment reads measured 0 conflicts (R4).
__device__ __forceinline__ int swz(int b) { return b ^ ((b >> 3) & 0x30); }

// ---------------- prepass: fp32 -> bf16 for x and hw ----------------
__global__ __launch_bounds__(256)
void cvt_bf16(const float* __restrict__ x, const float* __restrict__ hw,
              unsigned short* __restrict__ xb, unsigned short* __restrict__ wb)
{
    const long long NX = 8192LL * 4096;
    const long long NW = 5LL * 16 * 256 * 256;
    const long long total8 = (NX + NW) / 8;
    for (long long i = (long long)blockIdx.x * 256 + threadIdx.x; i < total8;
         i += (long long)gridDim.x * 256) {
        long long e = i * 8;
        const float* src;
        unsigned short* dst;
        long long off;
        if (e < NX) { src = x;  dst = xb; off = e; }
        else        { src = hw; dst = wb; off = e - NX; }
        float4 f0 = *(const float4*)(src + off);
        float4 f1 = *(const float4*)(src + off + 4);
        ushort4 u0, u1;
        u0.x = f2bf(f0.x); u0.y = f2bf(f0.y); u0.z = f2bf(f0.z); u0.w = f2bf(f0.w);
        u1.x = f2bf(f1.x); u1.y = f2bf(f1.y); u1.z = f2bf(f1.z); u1.w = f2bf(f1.w);
        *(ushort4*)(dst + off)     = u0;
        *(ushort4*)(dst + off + 4) = u1;
    }
}

// -------- main GEMM: 128x256 tile, 4 waves, 3-buffer counted-vmcnt, 2 blocks/CU --------
__global__ __launch_bounds__(256, 2)
void hcl_gemm4(const unsigned short* __restrict__ xb,
               const unsigned short* __restrict__ wb,
               const float* __restrict__ hb,
               float* __restrict__ out)
{
    extern __shared__ unsigned short lds[];   // 3 * 24KB

    const int tid  = threadIdx.x;             // 0..255
    const int lane = tid & 63;
    const int wave = tid >> 6;                // 0..3 = n-quarter of tile
    const int ln15 = lane & 15;
    const int hi   = lane >> 4;               // 0..3

    const int bm0 = blockIdx.x * 128;
    const int p   = blockIdx.y;               // 0..15

    // ---- staging geometry: physical byte p_j = j*4096 + tid*16, data at swz(p_j)
    int rj[4], cj[4];
    #pragma unroll
    for (int j = 0; j < 4; ++j) {
        int g = swz(j * 4096 + tid * 16);
        rj[j] = g >> 6;            // row (64B rows)
        cj[j] = (g & 63) >> 1;     // col in shorts
    }

    // ---- fragment read offsets (swizzled byte offsets) ----
    int offA[8], offB[4];
    #pragma unroll
    for (int mf = 0; mf < 8; ++mf)
        offA[mf] = swz((mf * 16 + ln15) * 64 + hi * 16);
    #pragma unroll
    for (int nf = 0; nf < 4; ++nf)
        offB[nf] = swz((wave * 64 + nf * 16 + ln15) * 64 + hi * 16);

    f32x4 acc[8][4] = {};

    auto STAGE = [&](int kt, int buf) {
        const int t = kt >> 3;
        const int s = p ^ ((1 << t) >> 1);
        const unsigned short* ga = xb + (size_t)bm0 * INF + s * 256 + (kt & 7) * 32;
        const unsigned short* gb = wb + ((size_t)(t * 16 + s) << 16) + (kt & 7) * 32;
        char* lb = (char*)lds + buf * BUFB + wave * 1024;
        // A tile [128][32]: 8KB = 2 insts of 4KB
        gl_lds16(ga + (size_t)rj[0] * INF + cj[0], lb);
        gl_lds16(ga + (size_t)rj[1] * INF + cj[1], lb + 4096);
        // B tile [256][32]: 16KB = 4 insts of 4KB, LDS base +8192
        gl_lds16(gb + (size_t)rj[0] * 256 + cj[0], lb + 8192);
        gl_lds16(gb + (size_t)rj[1] * 256 + cj[1], lb + 8192 + 4096);
        gl_lds16(gb + (size_t)rj[2] * 256 + cj[2], lb + 8192 + 8192);
        gl_lds16(gb + (size_t)rj[3] * 256 + cj[3], lb + 8192 + 12288);
    };

    auto COMPUTE = [&](int buf) {
        const char* LA = (const char*)lds + buf * BUFB;
        const char* LB = LA + 8192;
        short8 fa[8], fb[4];
        #pragma unroll
        for (int nf = 0; nf < 4; ++nf) fb[nf] = *(const short8*)(LB + offB[nf]);
        #pragma unroll
        for (int mf = 0; mf < 8; ++mf) fa[mf] = *(const short8*)(LA + offA[mf]);
        __builtin_amdgcn_s_setprio(1);
        #pragma unroll
        for (int mf = 0; mf < 8; ++mf)
            #pragma unroll
            for (int nf = 0; nf < 4; ++nf)
                acc[mf][nf] = __builtin_amdgcn_mfma_f32_16x16x32_bf16(
                    fa[mf], fb[nf], acc[mf][nf], 0, 0, 0);
        __builtin_amdgcn_s_setprio(0);
    };

    // ---- prologue: fill pipeline 2 K-tiles deep ----
    STAGE(0, 0);
    STAGE(1, 1);

    // ---- main loop: issue kt+2, wait kt (vmcnt 12 = kt+1,kt+2 in flight) ----
    for (int kt = 0; kt < NKT - 2; ++kt) {
        STAGE(kt + 2, (kt + 2) % 3);
        asm volatile("s_waitcnt vmcnt(12)");
        __builtin_amdgcn_s_barrier();
        __builtin_amdgcn_sched_barrier(0);
        COMPUTE(kt % 3);
        __builtin_amdgcn_s_barrier();
        __builtin_amdgcn_sched_barrier(0);
    }
    // kt = NKT-2
    asm volatile("s_waitcnt vmcnt(6)");
    __builtin_amdgcn_s_barrier();
    __builtin_amdgcn_sched_barrier(0);
    COMPUTE((NKT - 2) % 3);
    __builtin_amdgcn_s_barrier();
    // kt = NKT-1
    asm volatile("s_waitcnt vmcnt(0)");
    __builtin_amdgcn_s_barrier();
    __builtin_amdgcn_sched_barrier(0);
    COMPUTE((NKT - 1) % 3);

    // ---- epilogue: C/D layout col = lane&15, row = (lane>>4)*4 + r ----
    const int col0 = p * 256 + wave * 64;
    #pragma unroll
    for (int nf = 0; nf < 4; ++nf) {
        const int col = col0 + nf * 16 + ln15;
        const float bias = hb[col];
        #pragma unroll
        for (int mf = 0; mf < 8; ++mf) {
            #pragma unroll
            for (int r = 0; r < 4; ++r) {
                const int row = bm0 + mf * 16 + hi * 4 + r;
                out[(size_t)row * 4096 + col] = acc[mf][nf][r] + bias;
            }
        }
    }
}

// ---------------- fallback (round-1 fused kernel) if ws too small ----------------
__global__ __launch_bounds__(256)
void hcl_mfma_fused(const float* __restrict__ x,
                    const float* __restrict__ hw,
                    const float* __restrict__ hb,
                    float* __restrict__ out)
{
    __shared__ unsigned short As[128][32];
    __shared__ unsigned short Bs[128][32];

    const int tid  = threadIdx.x;
    const int lane = tid & 63;
    const int wave = tid >> 6;
    const int wr   = wave >> 1, wc = wave & 1;

    const int bm0 = blockIdx.x * 128;
    const int p   = blockIdx.y >> 1;
    const int nh  = blockIdx.y & 1;

    f32x4 acc[4][4] = {};

    const int srow = tid >> 3;
    const int scol = (tid & 7) * 4;

    #pragma unroll
    for (int t = 0; t < 5; ++t) {
        const int mask = (t == 0) ? 0 : (1 << (t - 1));
        const int s = p ^ mask;
        const float* xchunk = x  + (size_t)bm0 * INF + s * 256;
        const float* wchunk = hw + ((size_t)(t * 16 + s) * 256 + nh * 128) * 256;

        for (int k8 = 0; k8 < 8; ++k8) {
            const int kc = k8 * 32;
            #pragma unroll
            for (int i = 0; i < 4; ++i) {
                const int row = i * 32 + srow;
                float4 fa = *(const float4*)(xchunk + (size_t)row * INF + kc + scol);
                float4 fb = *(const float4*)(wchunk + (size_t)row * 256 + kc + scol);
                ushort4 ua, ub;
                ua.x = f2bf(fa.x); ua.y = f2bf(fa.y);
                ua.z = f2bf(fa.z); ua.w = f2bf(fa.w);
                ub.x = f2bf(fb.x); ub.y = f2bf(fb.y);
                ub.z = f2bf(fb.z); ub.w = f2bf(fb.w);
                *(ushort4*)&As[row][scol] = ua;
                *(ushort4*)&Bs[row][scol] = ub;
            }
            __syncthreads();

            short8 a[4], b[4];
            #pragma unroll
            for (int mi = 0; mi < 4; ++mi)
                a[mi] = *(const short8*)&As[wr * 64 + mi * 16 + (lane & 15)][(lane >> 4) * 8];
            #pragma unroll
            for (int nj = 0; nj < 4; ++nj)
                b[nj] = *(const short8*)&Bs[wc * 64 + nj * 16 + (lane & 15)][(lane >> 4) * 8];

            #pragma unroll
            for (int mi = 0; mi < 4; ++mi)
                #pragma unroll
                for (int nj = 0; nj < 4; ++nj)
                    acc[mi][nj] = __builtin_amdgcn_mfma_f32_16x16x32_bf16(
                        a[mi], b[nj], acc[mi][nj], 0, 0, 0);

            __syncthreads();
        }
    }

    const int col0 = p * 256 + nh * 128 + wc * 64;
    #pragma unroll
    for (int nj = 0; nj < 4; ++nj) {
        const int col = col0 + nj * 16 + (lane & 15);
        const float bias = hb[col];
        #pragma unroll
        for (int mi = 0; mi < 4; ++mi) {
            #pragma unroll
            for (int r = 0; r < 4; ++r) {
                const int row = bm0 + wr * 64 + mi * 16 + (lane >> 4) * 4 + r;
                out[(size_t)row * 4096 + col] = acc[mi][nj][r] + bias;
            }
        }
    }
}

extern "C" void kernel_launch(void* const* d_in, const int* in_sizes, int n_in,
                              void* d_out, int out_size, void* d_ws, size_t ws_size,
                              hipStream_t stream) {
    const float* x  = (const float*)d_in[0];   // [8192, 4096]
    const float* hw = (const float*)d_in[1];   // [5, 16, 256, 256]
    const float* hb = (const float*)d_in[2];   // [4096]
    float* out = (float*)d_out;                // [8192, 4096]

    const size_t NX = 8192ull * 4096;
    const size_t NW = 5ull * 16 * 256 * 256;
    const size_t need = (NX + NW) * sizeof(unsigned short);

    if (ws_size >= need) {
        unsigned short* xb = (unsigned short*)d_ws;
        unsigned short* wb = xb + NX;
        cvt_bf16<<<2048, 256, 0, stream>>>(x, hw, xb, wb);
        dim3 grid(8192 / 128, 16);
        hcl_gemm4<<<grid, 256, 3 * BUFB, stream>>>(xb, wb, hb, out);
    } else {
        dim3 grid(8192 / 128, 32);
        hcl_mfma_fused<<<grid, 256, 0, stream>>>(x, hw, hb, out);
    }
}